// Round 1
// baseline (255.928 us; speedup 1.0000x reference)
//
#include <hip/hip_runtime.h>
#include <hip/hip_bf16.h>
#include <stdint.h>

#define B_N   16
#define C_N   256
#define W_N   64
#define HW_N  4096
#define CK_N  32      // f,g channels
#define CH_N  128     // h channels
#define HWP_N 1024    // pooled spatial
#define MR_N  192     // CK+CK+CH rows in fused conv weight

typedef __attribute__((ext_vector_type(8))) short short8;
typedef __attribute__((ext_vector_type(4))) float f32x4;
typedef __attribute__((ext_vector_type(4))) unsigned uint4v;

#define MFMA(a, b, c) __builtin_amdgcn_mfma_f32_16x16x32_bf16((a), (b), (c), 0, 0, 0)

__device__ __forceinline__ unsigned short f2bf(float f) {
    union { float f; unsigned u; } v; v.f = f;
    unsigned r = v.u + 0x7FFFu + ((v.u >> 16) & 1u);   // RNE
    return (unsigned short)(r >> 16);
}
// round-half-up bf16 pair pack: 3 VALU ops (add, add, v_perm)
__device__ __forceinline__ unsigned packrn(float lo, float hi) {
    unsigned a = __float_as_uint(lo) + 0x8000u;
    unsigned b = __float_as_uint(hi) + 0x8000u;
    return __builtin_amdgcn_perm(b, a, 0x07060302);  // (a>>16)|(b&0xFFFF0000)
}
__device__ __forceinline__ short8 ld8(const void* p) {
    return *reinterpret_cast<const short8*>(p);
}

// ---------------- kernel 0: cast weights to bf16 ----------------
__global__ __launch_bounds__(256) void k_prep(
    const float* __restrict__ wf, const float* __restrict__ wg,
    const float* __restrict__ wh, const float* __restrict__ wv,
    unsigned short* __restrict__ Wc, unsigned short* __restrict__ Wv)
{
    int i = blockIdx.x * 256 + threadIdx.x;
    if (i < MR_N * C_N) {
        int r = i / C_N, c = i % C_N;
        float v = (r < 32) ? wf[r * C_N + c]
                : (r < 64) ? wg[(r - 32) * C_N + c]
                           : wh[(r - 64) * C_N + c];
        Wc[i] = f2bf(v);
    }
    if (i < C_N * CH_N) Wv[i] = f2bf(wv[i]);
}

// ---------------- kernel 1: fused conv1x1 (f,g,h) + 2x2 maxpool ----------------
// f_/g_/h_ all bf16.
__global__ __launch_bounds__(256) void k_conv_fgh(
    const float* __restrict__ x, const unsigned short* __restrict__ Wc,
    const float* __restrict__ bfp, const float* __restrict__ bgp, const float* __restrict__ bhp,
    unsigned short* __restrict__ f_, unsigned short* __restrict__ g_, unsigned short* __restrict__ h_)
{
    __shared__ __align__(16) unsigned char lds[64 * 512];
    const int T = threadIdx.x;
    const int lane = T & 63, wid = T >> 6;
    const int blk = blockIdx.x;
    const int b = blk >> 6;
    const int seg = blk & 63;
    const int rp = seg >> 1;     // pooled row 0..31
    const int half = seg & 1;    // which 32-wide half of the row pair
    const float* xb = x + (size_t)b * C_N * HW_N;

    // stage x -> LDS bf16 (transpose to [px][ch] with chunk-XOR swizzle)
    #pragma unroll
    for (int i = 0; i < 8; ++i) {
        int task = i * 256 + T;        // 0..2047 = 16 px-quads x 128 ch-pairs
        int pq = task & 15;
        int cp = task >> 4;            // channel pair 0..127
        int px0 = pq * 4;
        int row = 2 * rp + (px0 >> 5);
        int wcol = half * 32 + (px0 & 31);
        const float4 v0 = *reinterpret_cast<const float4*>(xb + (size_t)(2 * cp) * HW_N + row * W_N + wcol);
        const float4 v1 = *reinterpret_cast<const float4*>(xb + (size_t)(2 * cp + 1) * HW_N + row * W_N + wcol);
        float vlo[4] = {v0.x, v0.y, v0.z, v0.w};
        float vhi[4] = {v1.x, v1.y, v1.z, v1.w};
        int kc = cp >> 2, co = cp & 3;
        #pragma unroll
        for (int j = 0; j < 4; ++j) {
            int px = px0 + j;
            *reinterpret_cast<unsigned*>(lds + px * 512 + ((kc ^ (px & 31)) << 4) + co * 4)
                = packrn(vlo[j], vhi[j]);
        }
    }
    __syncthreads();

    const int l15 = lane & 15, quad = lane >> 4;
    f32x4 acc[3][4];
    #pragma unroll
    for (int mt = 0; mt < 3; ++mt)
        #pragma unroll
        for (int nt = 0; nt < 4; ++nt)
            acc[mt][nt] = f32x4{0.f, 0.f, 0.f, 0.f};

    const int m0base = wid * 48;
    for (int k0 = 0; k0 < 256; k0 += 32) {
        short8 afr[3];
        #pragma unroll
        for (int mt = 0; mt < 3; ++mt)
            afr[mt] = ld8(Wc + (size_t)(m0base + mt * 16 + l15) * C_N + k0 + quad * 8);
        #pragma unroll
        for (int nt = 0; nt < 4; ++nt) {
            int px = nt * 16 + l15;
            int kc = (k0 >> 3) + quad;
            short8 bfr = ld8(lds + px * 512 + ((kc ^ (px & 31)) << 4));
            #pragma unroll
            for (int mt = 0; mt < 3; ++mt)
                acc[mt][nt] = MFMA(afr[mt], bfr, acc[mt][nt]);
        }
    }

    // epilogue: bias, pool, scatter to f/g/h
    #pragma unroll
    for (int mt = 0; mt < 3; ++mt) {
        int mbase = m0base + mt * 16;
        int mrow0 = mbase + quad * 4;
        float bias[4];
        #pragma unroll
        for (int r = 0; r < 4; ++r) {
            int m = mrow0 + r;
            bias[r] = (m < 32) ? bfp[m] : (m < 64) ? bgp[m - 32] : bhp[m - 64];
        }
        if (mbase < 32) {
            #pragma unroll
            for (int nt = 0; nt < 4; ++nt) {
                int px = nt * 16 + l15;
                int p = (2 * rp + (px >> 5)) * W_N + half * 32 + (px & 31);
                uint2 u;
                u.x = packrn(acc[mt][nt][0] + bias[0], acc[mt][nt][1] + bias[1]);
                u.y = packrn(acc[mt][nt][2] + bias[2], acc[mt][nt][3] + bias[3]);
                *reinterpret_cast<uint2*>(f_ + ((size_t)b * HW_N + p) * CK_N + mrow0) = u;
            }
        } else if (mbase < 64) {
            int gc0 = mrow0 - 32;
            #pragma unroll
            for (int nt = 0; nt < 2; ++nt) {
                float pv[4];
                #pragma unroll
                for (int r = 0; r < 4; ++r) {
                    float m1 = fmaxf(acc[mt][nt][r], acc[mt][nt + 2][r]);
                    pv[r] = fmaxf(m1, __shfl_xor(m1, 1)) + bias[r];
                }
                if ((lane & 1) == 0) {
                    int kp = rp * 32 + half * 16 + ((nt * 16 + l15) >> 1);
                    uint2 u;
                    u.x = packrn(pv[0], pv[1]);
                    u.y = packrn(pv[2], pv[3]);
                    *reinterpret_cast<uint2*>(g_ + ((size_t)b * HWP_N + kp) * CK_N + gc0) = u;
                }
            }
        } else {
            int hc0 = mrow0 - 64;
            #pragma unroll
            for (int nt = 0; nt < 2; ++nt) {
                float pv[4];
                #pragma unroll
                for (int r = 0; r < 4; ++r) {
                    float m1 = fmaxf(acc[mt][nt][r], acc[mt][nt + 2][r]);
                    pv[r] = fmaxf(m1, __shfl_xor(m1, 1)) + bias[r];
                }
                #pragma unroll
                for (int r = 0; r < 4; ++r) {
                    int lo = (int)(packrn(pv[r], pv[r]) & 0xFFFFu);  // bf16 bits
                    int hi = __shfl_down(lo, 2);
                    if ((lane & 3) == 0) {
                        int kp2 = rp * 32 + half * 16 + nt * 8 + (l15 >> 1);
                        *reinterpret_cast<unsigned*>(
                            h_ + ((size_t)b * CH_N + hc0 + r) * HWP_N + kp2)
                            = (unsigned)lo | ((unsigned)hi << 16);
                    }
                }
            }
        }
    }
}

// ---------------- kernel 2: fused attention ----------------
// 16 queries/wave, 4 waves/block, grid 1024 -> 4 blocks/CU. Fixed-shift softmax.
// V double-buffered in LDS (2 x [128ch][144B], bank-uniform b128 reads/writes):
// ONE barrier per 64-key chunk; chunk c+1 global loads overlap chunk c compute.
// PV uses K=32 MFMA: QK processes g rows in a permuted order
//   key(kt, m) = (kt>>1)*32 + (kt&1)*4 + 8*(m>>2) + (m&3)
// so that sp[2t] ++ sp[2t+1] packed as bf16 IS the 16x16x32 B-fragment
// (lane quad holds keys 8*quad..8*quad+7) -- zero cross-lane ops, and the V
// A-fragment is a natural-order contiguous ds_read_b128.
__global__ __launch_bounds__(256, 4) void k_attn(
    const unsigned short* __restrict__ f_, const unsigned short* __restrict__ g_,
    const unsigned short* __restrict__ h_, unsigned short* __restrict__ o_)
{
    __shared__ __align__(16) unsigned char Vl[2 * 18432];
    const int T = threadIdx.x;
    const int lane = T & 63, wid = T >> 6;
    const int l15 = lane & 15, quad = lane >> 4;

    const int blk = blockIdx.x;      // 1024 = 16 b x 64 qtiles(64q)
    const int b = blk >> 6;
    const int q0w = (blk & 63) * 64 + wid * 16;
    const unsigned short* fb = f_ + (size_t)b * HW_N * CK_N;
    const unsigned short* gb = g_ + (size_t)b * HWP_N * CK_N;
    const unsigned short* hb = h_ + (size_t)b * CH_N * HWP_N;

    short8 ffr = ld8(fb + (size_t)(q0w + l15) * CK_N + quad * 8);

    const f32x4 zf = {0.f, 0.f, 0.f, 0.f};
    f32x4 oacc[8];   // [ct]; D row = ch(quad*4+r), col = query(l15)
    #pragma unroll
    for (int ct = 0; ct < 8; ++ct)
        oacc[ct] = f32x4{0.f, 0.f, 0.f, 0.f};
    float lsum = 0.f;

    // staging coords: ch rows sch+32i (i<4), 16B key-chunk skq
    const int sch = T >> 3, skq = T & 7;
    // permuted in-tile key offset for QK A-operand rows
    const int kq = ((l15 >> 2) << 3) | (l15 & 3);

    uint4 vpre[4];
    #pragma unroll
    for (int i = 0; i < 4; ++i)
        vpre[i] = *reinterpret_cast<const uint4*>(hb + (size_t)(sch + i * 32) * HWP_N + skq * 8);
    short8 gcur[4];
    #pragma unroll
    for (int kt = 0; kt < 4; ++kt)
        gcur[kt] = ld8(gb + (size_t)(((kt >> 1) << 5) + ((kt & 1) << 2) + kq) * CK_N + quad * 8);

    for (int c = 0; c < 16; ++c) {
        unsigned char* buf = Vl + (c & 1) * 18432;
        // write chunk c's V (WAR on this buffer was cleared by iter c-1's barrier)
        #pragma unroll
        for (int i = 0; i < 4; ++i)
            *reinterpret_cast<uint4*>(buf + (sch + i * 32) * 144 + skq * 16) = vpre[i];
        // issue chunk c+1 global loads (land during chunk c compute)
        if (c < 15) {
            #pragma unroll
            for (int i = 0; i < 4; ++i)
                vpre[i] = *reinterpret_cast<const uint4*>(
                    hb + (size_t)(sch + i * 32) * HWP_N + (c + 1) * 64 + skq * 8);
        }
        __syncthreads();   // buf writes visible; single barrier per chunk

        // QK: sp[kt] row (quad,r) = key (kt>>1)*32 + (kt&1)*4 + 8*quad + r, col=q(l15)
        f32x4 sp[4];
        #pragma unroll
        for (int kt = 0; kt < 4; ++kt)
            sp[kt] = MFMA(gcur[kt], ffr, zf);
        if (c < 15) {
            #pragma unroll
            for (int kt = 0; kt < 4; ++kt)
                gcur[kt] = ld8(gb + (size_t)((c + 1) * 64 + ((kt >> 1) << 5) + ((kt & 1) << 2) + kq) * CK_N + quad * 8);
        }

        // exp2 fixed shift, accumulate denom, pack straight into K=32 B-frags
        unsigned pw[8];
        float lw = 0.f;
        #pragma unroll
        for (int kt = 0; kt < 4; ++kt) {
            float p0 = __builtin_amdgcn_exp2f(sp[kt][0] * 1.44269504f - 28.85390082f);
            float p1 = __builtin_amdgcn_exp2f(sp[kt][1] * 1.44269504f - 28.85390082f);
            float p2 = __builtin_amdgcn_exp2f(sp[kt][2] * 1.44269504f - 28.85390082f);
            float p3 = __builtin_amdgcn_exp2f(sp[kt][3] * 1.44269504f - 28.85390082f);
            lw += (p0 + p1) + (p2 + p3);
            pw[2 * kt]     = packrn(p0, p1);
            pw[2 * kt + 1] = packrn(p2, p3);
        }
        lsum += lw;
        // B-frag slice t: lane quad holds P[key=t*32+8*quad+j][q=l15], j=0..7
        short8 pfA = __builtin_bit_cast(short8, uint4v{pw[0], pw[1], pw[2], pw[3]});
        short8 pfB = __builtin_bit_cast(short8, uint4v{pw[4], pw[5], pw[6], pw[7]});

        // PV: A = V[ch=ct*16+l15][key=t*32+quad*8+j] (natural order, b128 LDS)
        const int vbase = l15 * 144 + quad * 16;
        #pragma unroll
        for (int ct = 0; ct < 8; ++ct) {
            short8 a0 = *reinterpret_cast<const short8*>(buf + vbase + ct * 2304);
            oacc[ct] = MFMA(a0, pfA, oacc[ct]);
            short8 a1 = *reinterpret_cast<const short8*>(buf + vbase + ct * 2304 + 64);
            oacc[ct] = MFMA(a1, pfB, oacc[ct]);
        }
    }

    // reduce denominator across quads (lanes share query = l15), scale, store
    lsum += __shfl_xor(lsum, 16); lsum += __shfl_xor(lsum, 32);
    const float rl = 1.f / lsum;
    unsigned short* ob = o_ + (size_t)b * HW_N * CH_N;
    const int q = q0w + l15;
    #pragma unroll
    for (int ct = 0; ct < 8; ++ct) {
        uint2 u;
        u.x = packrn(oacc[ct][0] * rl, oacc[ct][1] * rl);
        u.y = packrn(oacc[ct][2] * rl, oacc[ct][3] * rl);
        *reinterpret_cast<uint2*>(ob + (size_t)q * CH_N + ct * 16 + quad * 4) = u;
    }
}

// ---------------- kernel 3: final conv1x1 + gamma + residual ----------------
// No LDS, no barriers: each wave = independent 64px x 64oc task; o fragments
// read directly from global (o_ layout [px][128ch] IS the A-frag layout).
__global__ __launch_bounds__(256, 4) void k_out(
    const unsigned short* __restrict__ o_, const unsigned short* __restrict__ Wv,
    const float* __restrict__ bv, const float* __restrict__ x,
    const float* __restrict__ gamma_p, float* __restrict__ out)
{
    const int T = threadIdx.x;
    const int lane = T & 63, wid = T >> 6;
    const int l15 = lane & 15, quad = lane >> 4;
    const int w = blockIdx.x * 4 + wid;   // 4096 wave tasks
    const int b = w >> 8;
    const int rem = w & 255;              // 4 oc-tiles x 64 px-tiles
    const int oc0 = (rem >> 6) * 64;
    const int px0 = (rem & 63) * 64;
    const unsigned short* ob = o_ + ((size_t)b * HW_N + px0) * CH_N;

    f32x4 acc[4][4];   // acc[mt][nt]; D row=px(quad*4+r), col=oc(l15)
    #pragma unroll
    for (int mt = 0; mt < 4; ++mt)
        #pragma unroll
        for (int nt = 0; nt < 4; ++nt)
            acc[mt][nt] = f32x4{0.f, 0.f, 0.f, 0.f};

    #pragma unroll
    for (int k0 = 0; k0 < 128; k0 += 32) {
        short8 bfr[4];   // o fragments (A operand, m = px), straight from global
        #pragma unroll
        for (int nt = 0; nt < 4; ++nt)
            bfr[nt] = ld8(ob + (size_t)(nt * 16 + l15) * CH_N + k0 + quad * 8);
        #pragma unroll
        for (int mt = 0; mt < 4; ++mt) {
            short8 afr = ld8(Wv + (size_t)(oc0 + mt * 16 + l15) * CH_N + k0 + quad * 8);
            #pragma unroll
            for (int nt = 0; nt < 4; ++nt)
                acc[mt][nt] = MFMA(bfr[nt], afr, acc[mt][nt]);  // A=o(px), B=Wv(oc)
        }
    }

    const float gamma = *gamma_p;
    const float* xb = x + (size_t)b * C_N * HW_N;
    float* outb = out + (size_t)b * C_N * HW_N;
    #pragma unroll
    for (int mt = 0; mt < 4; ++mt) {
        int oc = oc0 + mt * 16 + l15;
        float bvv = bv[oc];
        #pragma unroll
        for (int nt = 0; nt < 4; ++nt) {
            size_t base = (size_t)oc * HW_N + px0 + nt * 16 + quad * 4;
            float4 xv = *reinterpret_cast<const float4*>(xb + base);
            float4 ov;
            ov.x = gamma * (acc[mt][nt][0] + bvv) + xv.x;
            ov.y = gamma * (acc[mt][nt][1] + bvv) + xv.y;
            ov.z = gamma * (acc[mt][nt][2] + bvv) + xv.z;
            ov.w = gamma * (acc[mt][nt][3] + bvv) + xv.w;
            *reinterpret_cast<float4*>(outb + base) = ov;
        }
    }
}

// ---------------- launch ----------------
extern "C" void kernel_launch(void* const* d_in, const int* in_sizes, int n_in,
                              void* d_out, int out_size, void* d_ws, size_t ws_size,
                              hipStream_t stream) {
    const float* x     = (const float*)d_in[0];
    const float* wf    = (const float*)d_in[1];
    const float* bf    = (const float*)d_in[2];
    const float* wg    = (const float*)d_in[3];
    const float* bg    = (const float*)d_in[4];
    const float* wh    = (const float*)d_in[5];
    const float* bh    = (const float*)d_in[6];
    const float* wv    = (const float*)d_in[7];
    const float* bv    = (const float*)d_in[8];
    const float* gamma = (const float*)d_in[9];
    float* out = (float*)d_out;
    char* ws = (char*)d_ws;

    unsigned short* f_ = (unsigned short*)(ws);                 //  4,194,304 B
    unsigned short* g_ = (unsigned short*)(ws + 4194304);       //  1,048,576 B
    unsigned short* h_ = (unsigned short*)(ws + 5242880);       //  4,194,304 B
    unsigned short* o_ = (unsigned short*)(ws + 9437184);       // 16,777,216 B
    unsigned short* Wc = (unsigned short*)(ws + 26214400);      //     98,304 B
    unsigned short* Wv = (unsigned short*)(ws + 26312704);      //     65,536 B

    k_prep<<<192, 256, 0, stream>>>(wf, wg, wh, wv, Wc, Wv);
    k_conv_fgh<<<1024, 256, 0, stream>>>(x, Wc, bf, bg, bh, f_, g_, h_);
    k_attn<<<1024, 256, 0, stream>>>(f_, g_, h_, o_);
    k_out<<<1024, 256, 0, stream>>>(o_, Wv, bv, x, gamma, out);
}

// Round 2
// 206.224 us; speedup vs baseline: 1.2410x; 1.2410x over previous
//
#include <hip/hip_runtime.h>
#include <hip/hip_bf16.h>
#include <stdint.h>

#define B_N   16
#define C_N   256
#define W_N   64
#define HW_N  4096
#define CK_N  32      // f,g channels
#define CH_N  128     // h channels
#define HWP_N 1024    // pooled spatial
#define MR_N  192     // CK+CK+CH rows in fused conv weight

typedef __attribute__((ext_vector_type(8))) short short8;
typedef __attribute__((ext_vector_type(4))) float f32x4;
typedef __attribute__((ext_vector_type(4))) unsigned uint4v;

#define MFMA(a, b, c) __builtin_amdgcn_mfma_f32_16x16x32_bf16((a), (b), (c), 0, 0, 0)

__device__ __forceinline__ unsigned short f2bf(float f) {
    union { float f; unsigned u; } v; v.f = f;
    unsigned r = v.u + 0x7FFFu + ((v.u >> 16) & 1u);   // RNE
    return (unsigned short)(r >> 16);
}
// round-half-up bf16 pair pack: 3 VALU ops (add, add, v_perm)
__device__ __forceinline__ unsigned packrn(float lo, float hi) {
    unsigned a = __float_as_uint(lo) + 0x8000u;
    unsigned b = __float_as_uint(hi) + 0x8000u;
    return __builtin_amdgcn_perm(b, a, 0x07060302);  // (a>>16)|(b&0xFFFF0000)
}
__device__ __forceinline__ short8 ld8(const void* p) {
    return *reinterpret_cast<const short8*>(p);
}

// ---------------- kernel 0: cast weights to bf16 ----------------
__global__ __launch_bounds__(256) void k_prep(
    const float* __restrict__ wf, const float* __restrict__ wg,
    const float* __restrict__ wh, const float* __restrict__ wv,
    unsigned short* __restrict__ Wc, unsigned short* __restrict__ Wv)
{
    int i = blockIdx.x * 256 + threadIdx.x;
    if (i < MR_N * C_N) {
        int r = i / C_N, c = i % C_N;
        float v = (r < 32) ? wf[r * C_N + c]
                : (r < 64) ? wg[(r - 32) * C_N + c]
                           : wh[(r - 64) * C_N + c];
        Wc[i] = f2bf(v);
    }
    if (i < C_N * CH_N) Wv[i] = f2bf(wv[i]);
}

// ---------------- kernel 1: fused conv1x1 (f,g,h) + 2x2 maxpool ----------------
// f_/g_/h_ all bf16.
__global__ __launch_bounds__(256) void k_conv_fgh(
    const float* __restrict__ x, const unsigned short* __restrict__ Wc,
    const float* __restrict__ bfp, const float* __restrict__ bgp, const float* __restrict__ bhp,
    unsigned short* __restrict__ f_, unsigned short* __restrict__ g_, unsigned short* __restrict__ h_)
{
    __shared__ __align__(16) unsigned char lds[64 * 512];
    const int T = threadIdx.x;
    const int lane = T & 63, wid = T >> 6;
    const int blk = blockIdx.x;
    const int b = blk >> 6;
    const int seg = blk & 63;
    const int rp = seg >> 1;     // pooled row 0..31
    const int half = seg & 1;    // which 32-wide half of the row pair
    const float* xb = x + (size_t)b * C_N * HW_N;

    // stage x -> LDS bf16 (transpose to [px][ch] with chunk-XOR swizzle)
    #pragma unroll
    for (int i = 0; i < 8; ++i) {
        int task = i * 256 + T;        // 0..2047 = 16 px-quads x 128 ch-pairs
        int pq = task & 15;
        int cp = task >> 4;            // channel pair 0..127
        int px0 = pq * 4;
        int row = 2 * rp + (px0 >> 5);
        int wcol = half * 32 + (px0 & 31);
        const float4 v0 = *reinterpret_cast<const float4*>(xb + (size_t)(2 * cp) * HW_N + row * W_N + wcol);
        const float4 v1 = *reinterpret_cast<const float4*>(xb + (size_t)(2 * cp + 1) * HW_N + row * W_N + wcol);
        float vlo[4] = {v0.x, v0.y, v0.z, v0.w};
        float vhi[4] = {v1.x, v1.y, v1.z, v1.w};
        int kc = cp >> 2, co = cp & 3;
        #pragma unroll
        for (int j = 0; j < 4; ++j) {
            int px = px0 + j;
            *reinterpret_cast<unsigned*>(lds + px * 512 + ((kc ^ (px & 31)) << 4) + co * 4)
                = packrn(vlo[j], vhi[j]);
        }
    }
    __syncthreads();

    const int l15 = lane & 15, quad = lane >> 4;
    f32x4 acc[3][4];
    #pragma unroll
    for (int mt = 0; mt < 3; ++mt)
        #pragma unroll
        for (int nt = 0; nt < 4; ++nt)
            acc[mt][nt] = f32x4{0.f, 0.f, 0.f, 0.f};

    const int m0base = wid * 48;
    for (int k0 = 0; k0 < 256; k0 += 32) {
        short8 afr[3];
        #pragma unroll
        for (int mt = 0; mt < 3; ++mt)
            afr[mt] = ld8(Wc + (size_t)(m0base + mt * 16 + l15) * C_N + k0 + quad * 8);
        #pragma unroll
        for (int nt = 0; nt < 4; ++nt) {
            int px = nt * 16 + l15;
            int kc = (k0 >> 3) + quad;
            short8 bfr = ld8(lds + px * 512 + ((kc ^ (px & 31)) << 4));
            #pragma unroll
            for (int mt = 0; mt < 3; ++mt)
                acc[mt][nt] = MFMA(afr[mt], bfr, acc[mt][nt]);
        }
    }

    // epilogue: bias, pool, scatter to f/g/h
    #pragma unroll
    for (int mt = 0; mt < 3; ++mt) {
        int mbase = m0base + mt * 16;
        int mrow0 = mbase + quad * 4;
        float bias[4];
        #pragma unroll
        for (int r = 0; r < 4; ++r) {
            int m = mrow0 + r;
            bias[r] = (m < 32) ? bfp[m] : (m < 64) ? bgp[m - 32] : bhp[m - 64];
        }
        if (mbase < 32) {
            #pragma unroll
            for (int nt = 0; nt < 4; ++nt) {
                int px = nt * 16 + l15;
                int p = (2 * rp + (px >> 5)) * W_N + half * 32 + (px & 31);
                uint2 u;
                u.x = packrn(acc[mt][nt][0] + bias[0], acc[mt][nt][1] + bias[1]);
                u.y = packrn(acc[mt][nt][2] + bias[2], acc[mt][nt][3] + bias[3]);
                *reinterpret_cast<uint2*>(f_ + ((size_t)b * HW_N + p) * CK_N + mrow0) = u;
            }
        } else if (mbase < 64) {
            int gc0 = mrow0 - 32;
            #pragma unroll
            for (int nt = 0; nt < 2; ++nt) {
                float pv[4];
                #pragma unroll
                for (int r = 0; r < 4; ++r) {
                    float m1 = fmaxf(acc[mt][nt][r], acc[mt][nt + 2][r]);
                    pv[r] = fmaxf(m1, __shfl_xor(m1, 1)) + bias[r];
                }
                if ((lane & 1) == 0) {
                    int kp = rp * 32 + half * 16 + ((nt * 16 + l15) >> 1);
                    uint2 u;
                    u.x = packrn(pv[0], pv[1]);
                    u.y = packrn(pv[2], pv[3]);
                    *reinterpret_cast<uint2*>(g_ + ((size_t)b * HWP_N + kp) * CK_N + gc0) = u;
                }
            }
        } else {
            int hc0 = mrow0 - 64;
            #pragma unroll
            for (int nt = 0; nt < 2; ++nt) {
                float pv[4];
                #pragma unroll
                for (int r = 0; r < 4; ++r) {
                    float m1 = fmaxf(acc[mt][nt][r], acc[mt][nt + 2][r]);
                    pv[r] = fmaxf(m1, __shfl_xor(m1, 1)) + bias[r];
                }
                #pragma unroll
                for (int r = 0; r < 4; ++r) {
                    int lo = (int)(packrn(pv[r], pv[r]) & 0xFFFFu);  // bf16 bits
                    int hi = __shfl_down(lo, 2);
                    if ((lane & 3) == 0) {
                        int kp2 = rp * 32 + half * 16 + nt * 8 + (l15 >> 1);
                        *reinterpret_cast<unsigned*>(
                            h_ + ((size_t)b * CH_N + hc0 + r) * HWP_N + kp2)
                            = (unsigned)lo | ((unsigned)hi << 16);
                    }
                }
            }
        }
    }
}

// ---------------- kernel 2: fused attention ----------------
// 16 queries/wave, 4 waves/block, grid 1024 -> 4 blocks/CU. Fixed-shift softmax.
// V double-buffered in LDS (2 x [128ch][136B]) -- round-0 verified-0-conflict
// layout: staging = two uint2 b64 writes, PV reads = b64 pairs (start dwords
// 2*l15 + 4*quad cover all 32 banks once per 16-lane phase).
// PV uses K=32 MFMA (half the issue slots of K=16): QK processes g rows in a
// permuted order  key(kt, m) = (kt>>1)*32 + (kt&1)*4 + 8*(m>>2) + (m&3)
// so sp[2t] ++ sp[2t+1] packed as bf16 IS the 16x16x32 B-fragment
// (lane quad holds keys 8*quad..8*quad+7) -- zero cross-lane ops. Each K=32
// A-fragment (16 contiguous V bytes) is assembled from two adjacent b64 reads.
__global__ __launch_bounds__(256, 4) void k_attn(
    const unsigned short* __restrict__ f_, const unsigned short* __restrict__ g_,
    const unsigned short* __restrict__ h_, unsigned short* __restrict__ o_)
{
    __shared__ __align__(16) unsigned char Vl[2 * 17408];
    const int T = threadIdx.x;
    const int lane = T & 63, wid = T >> 6;
    const int l15 = lane & 15, quad = lane >> 4;

    const int blk = blockIdx.x;      // 1024 = 16 b x 64 qtiles(64q)
    const int b = blk >> 6;
    const int q0w = (blk & 63) * 64 + wid * 16;
    const unsigned short* fb = f_ + (size_t)b * HW_N * CK_N;
    const unsigned short* gb = g_ + (size_t)b * HWP_N * CK_N;
    const unsigned short* hb = h_ + (size_t)b * CH_N * HWP_N;

    short8 ffr = ld8(fb + (size_t)(q0w + l15) * CK_N + quad * 8);

    const f32x4 zf = {0.f, 0.f, 0.f, 0.f};
    f32x4 oacc[8];   // [ct]; D row = ch(quad*4+r), col = query(l15)
    #pragma unroll
    for (int ct = 0; ct < 8; ++ct)
        oacc[ct] = f32x4{0.f, 0.f, 0.f, 0.f};
    float lsum = 0.f;

    // staging coords: ch rows sch+32i (i<4), 16B key-chunk skq (0-conflict)
    const int sch = T >> 3, skq = T & 7;
    // permuted in-tile key row for QK A-operand: l15 -> 8*(l15>>2) + (l15&3)
    const int kq = ((l15 >> 2) << 3) | (l15 & 3);

    uint4 vpre[4];
    #pragma unroll
    for (int i = 0; i < 4; ++i)
        vpre[i] = *reinterpret_cast<const uint4*>(hb + (size_t)(sch + i * 32) * HWP_N + skq * 8);
    short8 gcur[4];
    #pragma unroll
    for (int kt = 0; kt < 4; ++kt)
        gcur[kt] = ld8(gb + (size_t)(((kt >> 1) << 5) + ((kt & 1) << 2) + kq) * CK_N + quad * 8);

    for (int c = 0; c < 16; ++c) {
        unsigned char* buf = Vl + (c & 1) * 17408;
        // write chunk c's V (WAR on this buffer was cleared by iter c-1's barrier)
        #pragma unroll
        for (int i = 0; i < 4; ++i) {
            unsigned char* dst = buf + (sch + i * 32) * 136 + skq * 16;
            *reinterpret_cast<uint2*>(dst)     = uint2{vpre[i].x, vpre[i].y};
            *reinterpret_cast<uint2*>(dst + 8) = uint2{vpre[i].z, vpre[i].w};
        }
        // issue chunk c+1 global loads (land during chunk c compute)
        if (c < 15) {
            #pragma unroll
            for (int i = 0; i < 4; ++i)
                vpre[i] = *reinterpret_cast<const uint4*>(
                    hb + (size_t)(sch + i * 32) * HWP_N + (c + 1) * 64 + skq * 8);
        }
        __syncthreads();   // buf writes visible; single barrier per chunk

        // QK: sp[kt] row (quad,r) = key (kt>>1)*32 + (kt&1)*4 + 8*quad + r, col=q(l15)
        f32x4 sp[4];
        #pragma unroll
        for (int kt = 0; kt < 4; ++kt)
            sp[kt] = MFMA(gcur[kt], ffr, zf);
        if (c < 15) {
            #pragma unroll
            for (int kt = 0; kt < 4; ++kt)
                gcur[kt] = ld8(gb + (size_t)((c + 1) * 64 + ((kt >> 1) << 5) + ((kt & 1) << 2) + kq) * CK_N + quad * 8);
        }

        // exp2 fixed shift, accumulate denom, pack straight into K=32 B-frags
        unsigned pw[8];
        float lw = 0.f;
        #pragma unroll
        for (int kt = 0; kt < 4; ++kt) {
            float p0 = __builtin_amdgcn_exp2f(sp[kt][0] * 1.44269504f - 28.85390082f);
            float p1 = __builtin_amdgcn_exp2f(sp[kt][1] * 1.44269504f - 28.85390082f);
            float p2 = __builtin_amdgcn_exp2f(sp[kt][2] * 1.44269504f - 28.85390082f);
            float p3 = __builtin_amdgcn_exp2f(sp[kt][3] * 1.44269504f - 28.85390082f);
            lw += (p0 + p1) + (p2 + p3);
            pw[2 * kt]     = packrn(p0, p1);
            pw[2 * kt + 1] = packrn(p2, p3);
        }
        lsum += lw;
        // B-frag slice t: lane quad holds P[key=t*32+8*quad+j][q=l15], j=0..7
        short8 pfA = __builtin_bit_cast(short8, uint4v{pw[0], pw[1], pw[2], pw[3]});
        short8 pfB = __builtin_bit_cast(short8, uint4v{pw[4], pw[5], pw[6], pw[7]});

        // PV: A = V[ch=ct*16+l15][key=t*32+quad*8+j], two b64 reads per frag
        const int vbase = l15 * 136 + quad * 16;
        #pragma unroll
        for (int ct = 0; ct < 8; ++ct) {
            const unsigned char* p = buf + vbase + ct * 2176;
            uint2 aLo0 = *reinterpret_cast<const uint2*>(p);
            uint2 aLo1 = *reinterpret_cast<const uint2*>(p + 8);
            short8 a0 = __builtin_bit_cast(short8, uint4v{aLo0.x, aLo0.y, aLo1.x, aLo1.y});
            oacc[ct] = MFMA(a0, pfA, oacc[ct]);
            uint2 aHi0 = *reinterpret_cast<const uint2*>(p + 64);
            uint2 aHi1 = *reinterpret_cast<const uint2*>(p + 72);
            short8 a1 = __builtin_bit_cast(short8, uint4v{aHi0.x, aHi0.y, aHi1.x, aHi1.y});
            oacc[ct] = MFMA(a1, pfB, oacc[ct]);
        }
    }

    // reduce denominator across quads (lanes share query = l15), scale, store
    lsum += __shfl_xor(lsum, 16); lsum += __shfl_xor(lsum, 32);
    const float rl = 1.f / lsum;
    unsigned short* ob = o_ + (size_t)b * HW_N * CH_N;
    const int q = q0w + l15;
    #pragma unroll
    for (int ct = 0; ct < 8; ++ct) {
        uint2 u;
        u.x = packrn(oacc[ct][0] * rl, oacc[ct][1] * rl);
        u.y = packrn(oacc[ct][2] * rl, oacc[ct][3] * rl);
        *reinterpret_cast<uint2*>(ob + (size_t)q * CH_N + ct * 16 + quad * 4) = u;
    }
}

// ---------------- kernel 3: final conv1x1 + gamma + residual ----------------
// No LDS, no barriers: each wave = independent 64px x 64oc task; o fragments
// read directly from global (o_ layout [px][128ch] IS the A-frag layout).
__global__ __launch_bounds__(256, 4) void k_out(
    const unsigned short* __restrict__ o_, const unsigned short* __restrict__ Wv,
    const float* __restrict__ bv, const float* __restrict__ x,
    const float* __restrict__ gamma_p, float* __restrict__ out)
{
    const int T = threadIdx.x;
    const int lane = T & 63, wid = T >> 6;
    const int l15 = lane & 15, quad = lane >> 4;
    const int w = blockIdx.x * 4 + wid;   // 4096 wave tasks
    const int b = w >> 8;
    const int rem = w & 255;              // 4 oc-tiles x 64 px-tiles
    const int oc0 = (rem >> 6) * 64;
    const int px0 = (rem & 63) * 64;
    const unsigned short* ob = o_ + ((size_t)b * HW_N + px0) * CH_N;

    f32x4 acc[4][4];   // acc[mt][nt]; D row=px(quad*4+r), col=oc(l15)
    #pragma unroll
    for (int mt = 0; mt < 4; ++mt)
        #pragma unroll
        for (int nt = 0; nt < 4; ++nt)
            acc[mt][nt] = f32x4{0.f, 0.f, 0.f, 0.f};

    #pragma unroll
    for (int k0 = 0; k0 < 128; k0 += 32) {
        short8 bfr[4];   // o fragments (A operand, m = px), straight from global
        #pragma unroll
        for (int nt = 0; nt < 4; ++nt)
            bfr[nt] = ld8(ob + (size_t)(nt * 16 + l15) * CH_N + k0 + quad * 8);
        #pragma unroll
        for (int mt = 0; mt < 4; ++mt) {
            short8 afr = ld8(Wv + (size_t)(oc0 + mt * 16 + l15) * CH_N + k0 + quad * 8);
            #pragma unroll
            for (int nt = 0; nt < 4; ++nt)
                acc[mt][nt] = MFMA(bfr[nt], afr, acc[mt][nt]);  // A=o(px), B=Wv(oc)
        }
    }

    const float gamma = *gamma_p;
    const float* xb = x + (size_t)b * C_N * HW_N;
    float* outb = out + (size_t)b * C_N * HW_N;
    #pragma unroll
    for (int mt = 0; mt < 4; ++mt) {
        int oc = oc0 + mt * 16 + l15;
        float bvv = bv[oc];
        #pragma unroll
        for (int nt = 0; nt < 4; ++nt) {
            size_t base = (size_t)oc * HW_N + px0 + nt * 16 + quad * 4;
            float4 xv = *reinterpret_cast<const float4*>(xb + base);
            float4 ov;
            ov.x = gamma * (acc[mt][nt][0] + bvv) + xv.x;
            ov.y = gamma * (acc[mt][nt][1] + bvv) + xv.y;
            ov.z = gamma * (acc[mt][nt][2] + bvv) + xv.z;
            ov.w = gamma * (acc[mt][nt][3] + bvv) + xv.w;
            *reinterpret_cast<float4*>(outb + base) = ov;
        }
    }
}

// ---------------- launch ----------------
extern "C" void kernel_launch(void* const* d_in, const int* in_sizes, int n_in,
                              void* d_out, int out_size, void* d_ws, size_t ws_size,
                              hipStream_t stream) {
    const float* x     = (const float*)d_in[0];
    const float* wf    = (const float*)d_in[1];
    const float* bf    = (const float*)d_in[2];
    const float* wg    = (const float*)d_in[3];
    const float* bg    = (const float*)d_in[4];
    const float* wh    = (const float*)d_in[5];
    const float* bh    = (const float*)d_in[6];
    const float* wv    = (const float*)d_in[7];
    const float* bv    = (const float*)d_in[8];
    const float* gamma = (const float*)d_in[9];
    float* out = (float*)d_out;
    char* ws = (char*)d_ws;

    unsigned short* f_ = (unsigned short*)(ws);                 //  4,194,304 B
    unsigned short* g_ = (unsigned short*)(ws + 4194304);       //  1,048,576 B
    unsigned short* h_ = (unsigned short*)(ws + 5242880);       //  4,194,304 B
    unsigned short* o_ = (unsigned short*)(ws + 9437184);       // 16,777,216 B
    unsigned short* Wc = (unsigned short*)(ws + 26214400);      //     98,304 B
    unsigned short* Wv = (unsigned short*)(ws + 26312704);      //     65,536 B

    k_prep<<<192, 256, 0, stream>>>(wf, wg, wh, wv, Wc, Wv);
    k_conv_fgh<<<1024, 256, 0, stream>>>(x, Wc, bf, bg, bh, f_, g_, h_);
    k_attn<<<1024, 256, 0, stream>>>(f_, g_, h_, o_);
    k_out<<<1024, 256, 0, stream>>>(o_, Wv, bv, x, gamma, out);
}

// Round 5
// 202.851 us; speedup vs baseline: 1.2617x; 1.0166x over previous
//
#include <hip/hip_runtime.h>
#include <hip/hip_bf16.h>
#include <stdint.h>

#define B_N   16
#define C_N   256
#define W_N   64
#define HW_N  4096
#define CK_N  32      // f,g channels
#define CH_N  128     // h channels
#define HWP_N 1024    // pooled spatial
#define MR_N  192     // CK+CK+CH rows in fused conv weight

typedef __attribute__((ext_vector_type(8))) short short8;
typedef __attribute__((ext_vector_type(4))) float f32x4;
typedef __attribute__((ext_vector_type(4))) unsigned uint4v;

#define MFMA(a, b, c) __builtin_amdgcn_mfma_f32_16x16x32_bf16((a), (b), (c), 0, 0, 0)

__device__ __forceinline__ unsigned short f2bf(float f) {
    union { float f; unsigned u; } v; v.f = f;
    unsigned r = v.u + 0x7FFFu + ((v.u >> 16) & 1u);   // RNE
    return (unsigned short)(r >> 16);
}
// round-half-up bf16 pair pack: 3 VALU ops (add, add, v_perm)
__device__ __forceinline__ unsigned packrn(float lo, float hi) {
    unsigned a = __float_as_uint(lo) + 0x8000u;
    unsigned b = __float_as_uint(hi) + 0x8000u;
    return __builtin_amdgcn_perm(b, a, 0x07060302);  // (a>>16)|(b&0xFFFF0000)
}
__device__ __forceinline__ short8 ld8(const void* p) {
    return *reinterpret_cast<const short8*>(p);
}

// ---------------- kernel 0: cast weights to bf16 ----------------
__global__ __launch_bounds__(256) void k_prep(
    const float* __restrict__ wf, const float* __restrict__ wg,
    const float* __restrict__ wh, const float* __restrict__ wv,
    unsigned short* __restrict__ Wc, unsigned short* __restrict__ Wv)
{
    int i = blockIdx.x * 256 + threadIdx.x;
    if (i < MR_N * C_N) {
        int r = i / C_N, c = i % C_N;
        float v = (r < 32) ? wf[r * C_N + c]
                : (r < 64) ? wg[(r - 32) * C_N + c]
                           : wh[(r - 64) * C_N + c];
        Wc[i] = f2bf(v);
    }
    if (i < C_N * CH_N) Wv[i] = f2bf(wv[i]);
}

// ---------------- kernel 1: fused conv1x1 (f,g,h) + 2x2 maxpool ----------------
// f_/g_/h_ all bf16.
__global__ __launch_bounds__(256) void k_conv_fgh(
    const float* __restrict__ x, const unsigned short* __restrict__ Wc,
    const float* __restrict__ bfp, const float* __restrict__ bgp, const float* __restrict__ bhp,
    unsigned short* __restrict__ f_, unsigned short* __restrict__ g_, unsigned short* __restrict__ h_)
{
    __shared__ __align__(16) unsigned char lds[64 * 512];
    const int T = threadIdx.x;
    const int lane = T & 63, wid = T >> 6;
    const int blk = blockIdx.x;
    const int b = blk >> 6;
    const int seg = blk & 63;
    const int rp = seg >> 1;     // pooled row 0..31
    const int half = seg & 1;    // which 32-wide half of the row pair
    const float* xb = x + (size_t)b * C_N * HW_N;

    // stage x -> LDS bf16 (transpose to [px][ch] with chunk-XOR swizzle)
    #pragma unroll
    for (int i = 0; i < 8; ++i) {
        int task = i * 256 + T;        // 0..2047 = 16 px-quads x 128 ch-pairs
        int pq = task & 15;
        int cp = task >> 4;            // channel pair 0..127
        int px0 = pq * 4;
        int row = 2 * rp + (px0 >> 5);
        int wcol = half * 32 + (px0 & 31);
        const float4 v0 = *reinterpret_cast<const float4*>(xb + (size_t)(2 * cp) * HW_N + row * W_N + wcol);
        const float4 v1 = *reinterpret_cast<const float4*>(xb + (size_t)(2 * cp + 1) * HW_N + row * W_N + wcol);
        float vlo[4] = {v0.x, v0.y, v0.z, v0.w};
        float vhi[4] = {v1.x, v1.y, v1.z, v1.w};
        int kc = cp >> 2, co = cp & 3;
        #pragma unroll
        for (int j = 0; j < 4; ++j) {
            int px = px0 + j;
            *reinterpret_cast<unsigned*>(lds + px * 512 + ((kc ^ (px & 31)) << 4) + co * 4)
                = packrn(vlo[j], vhi[j]);
        }
    }
    __syncthreads();

    const int l15 = lane & 15, quad = lane >> 4;
    f32x4 acc[3][4];
    #pragma unroll
    for (int mt = 0; mt < 3; ++mt)
        #pragma unroll
        for (int nt = 0; nt < 4; ++nt)
            acc[mt][nt] = f32x4{0.f, 0.f, 0.f, 0.f};

    const int m0base = wid * 48;
    for (int k0 = 0; k0 < 256; k0 += 32) {
        short8 afr[3];
        #pragma unroll
        for (int mt = 0; mt < 3; ++mt)
            afr[mt] = ld8(Wc + (size_t)(m0base + mt * 16 + l15) * C_N + k0 + quad * 8);
        #pragma unroll
        for (int nt = 0; nt < 4; ++nt) {
            int px = nt * 16 + l15;
            int kc = (k0 >> 3) + quad;
            short8 bfr = ld8(lds + px * 512 + ((kc ^ (px & 31)) << 4));
            #pragma unroll
            for (int mt = 0; mt < 3; ++mt)
                acc[mt][nt] = MFMA(afr[mt], bfr, acc[mt][nt]);
        }
    }

    // epilogue: bias, pool, scatter to f/g/h
    #pragma unroll
    for (int mt = 0; mt < 3; ++mt) {
        int mbase = m0base + mt * 16;
        int mrow0 = mbase + quad * 4;
        float bias[4];
        #pragma unroll
        for (int r = 0; r < 4; ++r) {
            int m = mrow0 + r;
            bias[r] = (m < 32) ? bfp[m] : (m < 64) ? bgp[m - 32] : bhp[m - 64];
        }
        if (mbase < 32) {
            #pragma unroll
            for (int nt = 0; nt < 4; ++nt) {
                int px = nt * 16 + l15;
                int p = (2 * rp + (px >> 5)) * W_N + half * 32 + (px & 31);
                uint2 u;
                u.x = packrn(acc[mt][nt][0] + bias[0], acc[mt][nt][1] + bias[1]);
                u.y = packrn(acc[mt][nt][2] + bias[2], acc[mt][nt][3] + bias[3]);
                *reinterpret_cast<uint2*>(f_ + ((size_t)b * HW_N + p) * CK_N + mrow0) = u;
            }
        } else if (mbase < 64) {
            int gc0 = mrow0 - 32;
            #pragma unroll
            for (int nt = 0; nt < 2; ++nt) {
                float pv[4];
                #pragma unroll
                for (int r = 0; r < 4; ++r) {
                    float m1 = fmaxf(acc[mt][nt][r], acc[mt][nt + 2][r]);
                    pv[r] = fmaxf(m1, __shfl_xor(m1, 1)) + bias[r];
                }
                if ((lane & 1) == 0) {
                    int kp = rp * 32 + half * 16 + ((nt * 16 + l15) >> 1);
                    uint2 u;
                    u.x = packrn(pv[0], pv[1]);
                    u.y = packrn(pv[2], pv[3]);
                    *reinterpret_cast<uint2*>(g_ + ((size_t)b * HWP_N + kp) * CK_N + gc0) = u;
                }
            }
        } else {
            int hc0 = mrow0 - 64;
            #pragma unroll
            for (int nt = 0; nt < 2; ++nt) {
                float pv[4];
                #pragma unroll
                for (int r = 0; r < 4; ++r) {
                    float m1 = fmaxf(acc[mt][nt][r], acc[mt][nt + 2][r]);
                    pv[r] = fmaxf(m1, __shfl_xor(m1, 1)) + bias[r];
                }
                #pragma unroll
                for (int r = 0; r < 4; ++r) {
                    int lo = (int)(packrn(pv[r], pv[r]) & 0xFFFFu);  // bf16 bits
                    int hi = __shfl_down(lo, 2);
                    if ((lane & 3) == 0) {
                        int kp2 = rp * 32 + half * 16 + nt * 8 + (l15 >> 1);
                        *reinterpret_cast<unsigned*>(
                            h_ + ((size_t)b * CH_N + hc0 + r) * HWP_N + kp2)
                            = (unsigned)lo | ((unsigned)hi << 16);
                    }
                }
            }
        }
    }
}

// ---------------- kernel 2: fused attention ----------------
// 16 queries/wave, 4 waves/block, grid 1024 -> 4 blocks/CU. Fixed-shift softmax.
// V double-buffered in LDS (2 x [128ch][136B]) -- round-0 verified-0-conflict
// layout: staging = two uint2 b64 writes, PV reads = b64 pairs (start dwords
// 2*l15 + 4*quad cover all 32 banks once per 16-lane phase).
// PV uses K=32 MFMA (half the issue slots of K=16): QK processes g rows in a
// permuted order  key(kt, m) = (kt>>1)*32 + (kt&1)*4 + 8*(m>>2) + (m&3)
// so sp[2t] ++ sp[2t+1] packed as bf16 IS the 16x16x32 B-fragment
// (lane quad holds keys 8*quad..8*quad+7) -- zero cross-lane ops. Each K=32
// A-fragment (16 contiguous V bytes) is assembled from two adjacent b64 reads.
__global__ __launch_bounds__(256, 4) void k_attn(
    const unsigned short* __restrict__ f_, const unsigned short* __restrict__ g_,
    const unsigned short* __restrict__ h_, unsigned short* __restrict__ o_)
{
    __shared__ __align__(16) unsigned char Vl[2 * 17408];
    const int T = threadIdx.x;
    const int lane = T & 63, wid = T >> 6;
    const int l15 = lane & 15, quad = lane >> 4;

    const int blk = blockIdx.x;      // 1024 = 16 b x 64 qtiles(64q)
    const int b = blk >> 6;
    const int q0w = (blk & 63) * 64 + wid * 16;
    const unsigned short* fb = f_ + (size_t)b * HW_N * CK_N;
    const unsigned short* gb = g_ + (size_t)b * HWP_N * CK_N;
    const unsigned short* hb = h_ + (size_t)b * CH_N * HWP_N;

    short8 ffr = ld8(fb + (size_t)(q0w + l15) * CK_N + quad * 8);

    const f32x4 zf = {0.f, 0.f, 0.f, 0.f};
    f32x4 oacc[8];   // [ct]; D row = ch(quad*4+r), col = query(l15)
    #pragma unroll
    for (int ct = 0; ct < 8; ++ct)
        oacc[ct] = f32x4{0.f, 0.f, 0.f, 0.f};
    float lsum = 0.f;

    // staging coords: ch rows sch+32i (i<4), 16B key-chunk skq (0-conflict)
    const int sch = T >> 3, skq = T & 7;
    // permuted in-tile key row for QK A-operand: l15 -> 8*(l15>>2) + (l15&3)
    const int kq = ((l15 >> 2) << 3) | (l15 & 3);

    uint4 vpre[4];
    #pragma unroll
    for (int i = 0; i < 4; ++i)
        vpre[i] = *reinterpret_cast<const uint4*>(hb + (size_t)(sch + i * 32) * HWP_N + skq * 8);
    short8 gcur[4];
    #pragma unroll
    for (int kt = 0; kt < 4; ++kt)
        gcur[kt] = ld8(gb + (size_t)(((kt >> 1) << 5) + ((kt & 1) << 2) + kq) * CK_N + quad * 8);

    for (int c = 0; c < 16; ++c) {
        unsigned char* buf = Vl + (c & 1) * 17408;
        // write chunk c's V (WAR on this buffer was cleared by iter c-1's barrier)
        #pragma unroll
        for (int i = 0; i < 4; ++i) {
            unsigned char* dst = buf + (sch + i * 32) * 136 + skq * 16;
            *reinterpret_cast<uint2*>(dst)     = uint2{vpre[i].x, vpre[i].y};
            *reinterpret_cast<uint2*>(dst + 8) = uint2{vpre[i].z, vpre[i].w};
        }
        // issue chunk c+1 global loads (land during chunk c compute)
        if (c < 15) {
            #pragma unroll
            for (int i = 0; i < 4; ++i)
                vpre[i] = *reinterpret_cast<const uint4*>(
                    hb + (size_t)(sch + i * 32) * HWP_N + (c + 1) * 64 + skq * 8);
        }
        __syncthreads();   // buf writes visible; single barrier per chunk

        // QK: sp[kt] row (quad,r) = key (kt>>1)*32 + (kt&1)*4 + 8*quad + r, col=q(l15)
        f32x4 sp[4];
        #pragma unroll
        for (int kt = 0; kt < 4; ++kt)
            sp[kt] = MFMA(gcur[kt], ffr, zf);
        if (c < 15) {
            #pragma unroll
            for (int kt = 0; kt < 4; ++kt)
                gcur[kt] = ld8(gb + (size_t)((c + 1) * 64 + ((kt >> 1) << 5) + ((kt & 1) << 2) + kq) * CK_N + quad * 8);
        }

        // exp2 fixed shift, accumulate denom, pack straight into K=32 B-frags
        unsigned pw[8];
        float lw = 0.f;
        #pragma unroll
        for (int kt = 0; kt < 4; ++kt) {
            float p0 = __builtin_amdgcn_exp2f(sp[kt][0] * 1.44269504f - 28.85390082f);
            float p1 = __builtin_amdgcn_exp2f(sp[kt][1] * 1.44269504f - 28.85390082f);
            float p2 = __builtin_amdgcn_exp2f(sp[kt][2] * 1.44269504f - 28.85390082f);
            float p3 = __builtin_amdgcn_exp2f(sp[kt][3] * 1.44269504f - 28.85390082f);
            lw += (p0 + p1) + (p2 + p3);
            pw[2 * kt]     = packrn(p0, p1);
            pw[2 * kt + 1] = packrn(p2, p3);
        }
        lsum += lw;
        // B-frag slice t: lane quad holds P[key=t*32+8*quad+j][q=l15], j=0..7
        short8 pfA = __builtin_bit_cast(short8, uint4v{pw[0], pw[1], pw[2], pw[3]});
        short8 pfB = __builtin_bit_cast(short8, uint4v{pw[4], pw[5], pw[6], pw[7]});

        // PV: A = V[ch=ct*16+l15][key=t*32+quad*8+j], two b64 reads per frag
        const int vbase = l15 * 136 + quad * 16;
        #pragma unroll
        for (int ct = 0; ct < 8; ++ct) {
            const unsigned char* p = buf + vbase + ct * 2176;
            uint2 aLo0 = *reinterpret_cast<const uint2*>(p);
            uint2 aLo1 = *reinterpret_cast<const uint2*>(p + 8);
            short8 a0 = __builtin_bit_cast(short8, uint4v{aLo0.x, aLo0.y, aLo1.x, aLo1.y});
            oacc[ct] = MFMA(a0, pfA, oacc[ct]);
            uint2 aHi0 = *reinterpret_cast<const uint2*>(p + 64);
            uint2 aHi1 = *reinterpret_cast<const uint2*>(p + 72);
            short8 a1 = __builtin_bit_cast(short8, uint4v{aHi0.x, aHi0.y, aHi1.x, aHi1.y});
            oacc[ct] = MFMA(a1, pfB, oacc[ct]);
        }
    }

    // reduce denominator across quads (lanes share query = l15), scale, store
    lsum += __shfl_xor(lsum, 16); lsum += __shfl_xor(lsum, 32);
    const float rl = 1.f / lsum;
    unsigned short* ob = o_ + (size_t)b * HW_N * CH_N;
    const int q = q0w + l15;
    #pragma unroll
    for (int ct = 0; ct < 8; ++ct) {
        uint2 u;
        u.x = packrn(oacc[ct][0] * rl, oacc[ct][1] * rl);
        u.y = packrn(oacc[ct][2] * rl, oacc[ct][3] * rl);
        *reinterpret_cast<uint2*>(ob + (size_t)q * CH_N + ct * 16 + quad * 4) = u;
    }
}

// ---------------- kernel 3: final conv1x1 + gamma + residual ----------------
// No LDS, no barriers: each wave = independent 32px x 64oc task; o fragments
// read directly from global (o_ layout [px][128ch] IS the A-frag layout).
// 8192 wave tasks / grid 2048: k_out is latency-bound streaming (R2: 3.2 TB/s
// @ 28% occupancy). Halved tile doubles the grid; VGPR stays <=64 (R2 measured
// 64 with the FULL tile under the same (256,4) bound), so HW schedules
// 8 blocks/CU = 32 waves/CU without any launch-bounds change.
// NOTE: __launch_bounds__(256,8) suspected of killing the container (2x) --
// using the R2-proven (256,4) annotation instead; occupancy comes from
// resource fit, not the hint.
__global__ __launch_bounds__(256, 4) void k_out(
    const unsigned short* __restrict__ o_, const unsigned short* __restrict__ Wv,
    const float* __restrict__ bv, const float* __restrict__ x,
    const float* __restrict__ gamma_p, float* __restrict__ out)
{
    const int T = threadIdx.x;
    const int lane = T & 63, wid = T >> 6;
    const int l15 = lane & 15, quad = lane >> 4;
    const int w = blockIdx.x * 4 + wid;   // 8192 wave tasks
    const int b = w >> 9;
    const int rem = w & 511;              // 4 oc-tiles x 128 px-tiles
    const int oc0 = (rem >> 7) * 64;
    const int px0 = (rem & 127) * 32;
    const unsigned short* ob = o_ + ((size_t)b * HW_N + px0) * CH_N;

    f32x4 acc[4][2];   // acc[mt][nt]; D row=px(quad*4+r), col=oc(l15)
    #pragma unroll
    for (int mt = 0; mt < 4; ++mt)
        #pragma unroll
        for (int nt = 0; nt < 2; ++nt)
            acc[mt][nt] = f32x4{0.f, 0.f, 0.f, 0.f};

    #pragma unroll
    for (int k0 = 0; k0 < 128; k0 += 32) {
        short8 bfr[2];   // o fragments (A operand, m = px), straight from global
        #pragma unroll
        for (int nt = 0; nt < 2; ++nt)
            bfr[nt] = ld8(ob + (size_t)(nt * 16 + l15) * CH_N + k0 + quad * 8);
        #pragma unroll
        for (int mt = 0; mt < 4; ++mt) {
            short8 afr = ld8(Wv + (size_t)(oc0 + mt * 16 + l15) * CH_N + k0 + quad * 8);
            #pragma unroll
            for (int nt = 0; nt < 2; ++nt)
                acc[mt][nt] = MFMA(bfr[nt], afr, acc[mt][nt]);  // A=o(px), B=Wv(oc)
        }
    }

    const float gamma = *gamma_p;
    const float* xb = x + (size_t)b * C_N * HW_N;
    float* outb = out + (size_t)b * C_N * HW_N;
    #pragma unroll
    for (int mt = 0; mt < 4; ++mt) {
        int oc = oc0 + mt * 16 + l15;
        float bvv = bv[oc];
        #pragma unroll
        for (int nt = 0; nt < 2; ++nt) {
            size_t base = (size_t)oc * HW_N + px0 + nt * 16 + quad * 4;
            float4 xv = *reinterpret_cast<const float4*>(xb + base);
            float4 ov;
            ov.x = gamma * (acc[mt][nt][0] + bvv) + xv.x;
            ov.y = gamma * (acc[mt][nt][1] + bvv) + xv.y;
            ov.z = gamma * (acc[mt][nt][2] + bvv) + xv.z;
            ov.w = gamma * (acc[mt][nt][3] + bvv) + xv.w;
            *reinterpret_cast<float4*>(outb + base) = ov;
        }
    }
}

// ---------------- launch ----------------
extern "C" void kernel_launch(void* const* d_in, const int* in_sizes, int n_in,
                              void* d_out, int out_size, void* d_ws, size_t ws_size,
                              hipStream_t stream) {
    const float* x     = (const float*)d_in[0];
    const float* wf    = (const float*)d_in[1];
    const float* bf    = (const float*)d_in[2];
    const float* wg    = (const float*)d_in[3];
    const float* bg    = (const float*)d_in[4];
    const float* wh    = (const float*)d_in[5];
    const float* bh    = (const float*)d_in[6];
    const float* wv    = (const float*)d_in[7];
    const float* bv    = (const float*)d_in[8];
    const float* gamma = (const float*)d_in[9];
    float* out = (float*)d_out;
    char* ws = (char*)d_ws;

    unsigned short* f_ = (unsigned short*)(ws);                 //  4,194,304 B
    unsigned short* g_ = (unsigned short*)(ws + 4194304);       //  1,048,576 B
    unsigned short* h_ = (unsigned short*)(ws + 5242880);       //  4,194,304 B
    unsigned short* o_ = (unsigned short*)(ws + 9437184);       // 16,777,216 B
    unsigned short* Wc = (unsigned short*)(ws + 26214400);      //     98,304 B
    unsigned short* Wv = (unsigned short*)(ws + 26312704);      //     65,536 B

    k_prep<<<192, 256, 0, stream>>>(wf, wg, wh, wv, Wc, Wv);
    k_conv_fgh<<<1024, 256, 0, stream>>>(x, Wc, bf, bg, bh, f_, g_, h_);
    k_attn<<<1024, 256, 0, stream>>>(f_, g_, h_, o_);
    k_out<<<2048, 256, 0, stream>>>(o_, Wv, bv, x, gamma, out);
}

// Round 7
// 182.712 us; speedup vs baseline: 1.4007x; 1.1102x over previous
//
#include <hip/hip_runtime.h>
#include <hip/hip_bf16.h>
#include <stdint.h>

#define B_N   16
#define C_N   256
#define W_N   64
#define HW_N  4096
#define CK_N  32      // f,g channels
#define CH_N  128     // h channels
#define HWP_N 1024    // pooled spatial
#define MR_N  192     // CK+CK+CH rows in fused conv weight

typedef __attribute__((ext_vector_type(8))) short short8;
typedef __attribute__((ext_vector_type(4))) float f32x4;
typedef __attribute__((ext_vector_type(4))) unsigned uint4v;

#define MFMA(a, b, c) __builtin_amdgcn_mfma_f32_16x16x32_bf16((a), (b), (c), 0, 0, 0)

__device__ __forceinline__ unsigned short f2bf(float f) {
    union { float f; unsigned u; } v; v.f = f;
    unsigned r = v.u + 0x7FFFu + ((v.u >> 16) & 1u);   // RNE
    return (unsigned short)(r >> 16);
}
// round-half-up bf16 pair pack: 3 VALU ops (add, add, v_perm)
__device__ __forceinline__ unsigned packrn(float lo, float hi) {
    unsigned a = __float_as_uint(lo) + 0x8000u;
    unsigned b = __float_as_uint(hi) + 0x8000u;
    return __builtin_amdgcn_perm(b, a, 0x07060302);  // (a>>16)|(b&0xFFFF0000)
}
__device__ __forceinline__ short8 ld8(const void* p) {
    return *reinterpret_cast<const short8*>(p);
}

// ---------------- kernel 0: cast weights to bf16 ----------------
__global__ __launch_bounds__(256) void k_prep(
    const float* __restrict__ wf, const float* __restrict__ wg,
    const float* __restrict__ wh, const float* __restrict__ wv,
    unsigned short* __restrict__ Wc, unsigned short* __restrict__ Wv)
{
    int i = blockIdx.x * 256 + threadIdx.x;
    if (i < MR_N * C_N) {
        int r = i / C_N, c = i % C_N;
        float v = (r < 32) ? wf[r * C_N + c]
                : (r < 64) ? wg[(r - 32) * C_N + c]
                           : wh[(r - 64) * C_N + c];
        Wc[i] = f2bf(v);
    }
    if (i < C_N * CH_N) Wv[i] = f2bf(wv[i]);
}

// ---------------- kernel 1: fused conv1x1 (f,g,h) + 2x2 maxpool ----------------
// f_/g_/h_ all bf16.
__global__ __launch_bounds__(256) void k_conv_fgh(
    const float* __restrict__ x, const unsigned short* __restrict__ Wc,
    const float* __restrict__ bfp, const float* __restrict__ bgp, const float* __restrict__ bhp,
    unsigned short* __restrict__ f_, unsigned short* __restrict__ g_, unsigned short* __restrict__ h_)
{
    __shared__ __align__(16) unsigned char lds[64 * 512];
    const int T = threadIdx.x;
    const int lane = T & 63, wid = T >> 6;
    const int blk = blockIdx.x;
    const int b = blk >> 6;
    const int seg = blk & 63;
    const int rp = seg >> 1;     // pooled row 0..31
    const int half = seg & 1;    // which 32-wide half of the row pair
    const float* xb = x + (size_t)b * C_N * HW_N;

    // stage x -> LDS bf16 (transpose to [px][ch] with chunk-XOR swizzle)
    #pragma unroll
    for (int i = 0; i < 8; ++i) {
        int task = i * 256 + T;        // 0..2047 = 16 px-quads x 128 ch-pairs
        int pq = task & 15;
        int cp = task >> 4;            // channel pair 0..127
        int px0 = pq * 4;
        int row = 2 * rp + (px0 >> 5);
        int wcol = half * 32 + (px0 & 31);
        const float4 v0 = *reinterpret_cast<const float4*>(xb + (size_t)(2 * cp) * HW_N + row * W_N + wcol);
        const float4 v1 = *reinterpret_cast<const float4*>(xb + (size_t)(2 * cp + 1) * HW_N + row * W_N + wcol);
        float vlo[4] = {v0.x, v0.y, v0.z, v0.w};
        float vhi[4] = {v1.x, v1.y, v1.z, v1.w};
        int kc = cp >> 2, co = cp & 3;
        #pragma unroll
        for (int j = 0; j < 4; ++j) {
            int px = px0 + j;
            *reinterpret_cast<unsigned*>(lds + px * 512 + ((kc ^ (px & 31)) << 4) + co * 4)
                = packrn(vlo[j], vhi[j]);
        }
    }
    __syncthreads();

    const int l15 = lane & 15, quad = lane >> 4;
    f32x4 acc[3][4];
    #pragma unroll
    for (int mt = 0; mt < 3; ++mt)
        #pragma unroll
        for (int nt = 0; nt < 4; ++nt)
            acc[mt][nt] = f32x4{0.f, 0.f, 0.f, 0.f};

    const int m0base = wid * 48;
    for (int k0 = 0; k0 < 256; k0 += 32) {
        short8 afr[3];
        #pragma unroll
        for (int mt = 0; mt < 3; ++mt)
            afr[mt] = ld8(Wc + (size_t)(m0base + mt * 16 + l15) * C_N + k0 + quad * 8);
        #pragma unroll
        for (int nt = 0; nt < 4; ++nt) {
            int px = nt * 16 + l15;
            int kc = (k0 >> 3) + quad;
            short8 bfr = ld8(lds + px * 512 + ((kc ^ (px & 31)) << 4));
            #pragma unroll
            for (int mt = 0; mt < 3; ++mt)
                acc[mt][nt] = MFMA(afr[mt], bfr, acc[mt][nt]);
        }
    }

    // epilogue: bias, pool, scatter to f/g/h
    #pragma unroll
    for (int mt = 0; mt < 3; ++mt) {
        int mbase = m0base + mt * 16;
        int mrow0 = mbase + quad * 4;
        float bias[4];
        #pragma unroll
        for (int r = 0; r < 4; ++r) {
            int m = mrow0 + r;
            bias[r] = (m < 32) ? bfp[m] : (m < 64) ? bgp[m - 32] : bhp[m - 64];
        }
        if (mbase < 32) {
            #pragma unroll
            for (int nt = 0; nt < 4; ++nt) {
                int px = nt * 16 + l15;
                int p = (2 * rp + (px >> 5)) * W_N + half * 32 + (px & 31);
                uint2 u;
                u.x = packrn(acc[mt][nt][0] + bias[0], acc[mt][nt][1] + bias[1]);
                u.y = packrn(acc[mt][nt][2] + bias[2], acc[mt][nt][3] + bias[3]);
                *reinterpret_cast<uint2*>(f_ + ((size_t)b * HW_N + p) * CK_N + mrow0) = u;
            }
        } else if (mbase < 64) {
            int gc0 = mrow0 - 32;
            #pragma unroll
            for (int nt = 0; nt < 2; ++nt) {
                float pv[4];
                #pragma unroll
                for (int r = 0; r < 4; ++r) {
                    float m1 = fmaxf(acc[mt][nt][r], acc[mt][nt + 2][r]);
                    pv[r] = fmaxf(m1, __shfl_xor(m1, 1)) + bias[r];
                }
                if ((lane & 1) == 0) {
                    int kp = rp * 32 + half * 16 + ((nt * 16 + l15) >> 1);
                    uint2 u;
                    u.x = packrn(pv[0], pv[1]);
                    u.y = packrn(pv[2], pv[3]);
                    *reinterpret_cast<uint2*>(g_ + ((size_t)b * HWP_N + kp) * CK_N + gc0) = u;
                }
            }
        } else {
            int hc0 = mrow0 - 64;
            #pragma unroll
            for (int nt = 0; nt < 2; ++nt) {
                float pv[4];
                #pragma unroll
                for (int r = 0; r < 4; ++r) {
                    float m1 = fmaxf(acc[mt][nt][r], acc[mt][nt + 2][r]);
                    pv[r] = fmaxf(m1, __shfl_xor(m1, 1)) + bias[r];
                }
                #pragma unroll
                for (int r = 0; r < 4; ++r) {
                    int lo = (int)(packrn(pv[r], pv[r]) & 0xFFFFu);  // bf16 bits
                    int hi = __shfl_down(lo, 2);
                    if ((lane & 3) == 0) {
                        int kp2 = rp * 32 + half * 16 + nt * 8 + (l15 >> 1);
                        *reinterpret_cast<unsigned*>(
                            h_ + ((size_t)b * CH_N + hc0 + r) * HWP_N + kp2)
                            = (unsigned)lo | ((unsigned)hi << 16);
                    }
                }
            }
        }
    }
}

// ---------------- kernel 2: fused attention + final conv1x1 + residual ----------------
// 16 queries/wave, 4 waves/block, grid 1024 -> 4 blocks/CU. Fixed-shift softmax.
// V double-buffered in LDS (2 x [128ch][136B]) -- verified-0-conflict layout.
// PV uses K=32 MFMA via permuted-key QK (see R2 notes).
// k_out FUSED as epilogue: block's oacc IS the full o tile (64px x 128ch);
// o -> LDS [64px][264B] (256B payload + 8 pad; R6 BUG was reusing the V
// stride 136 < 256 -> row overlap). 64*264 = 16896 <= 17408 fits in Vl
// buffer 0, which no wave reads after chunk 15 (PV reads buffer 1 only),
// so no extra barrier before the o writes. 264B = 66 dw == 2 (mod 32):
// epilogue b64-pair reads land on start dwords 2*l15+4*quad+const -- the
// same measured-0-conflict family as the V reads.
__global__ __launch_bounds__(256, 4) void k_attn(
    const unsigned short* __restrict__ f_, const unsigned short* __restrict__ g_,
    const unsigned short* __restrict__ h_, const unsigned short* __restrict__ Wv,
    const float* __restrict__ bv, const float* __restrict__ x,
    const float* __restrict__ gamma_p, float* __restrict__ out)
{
    __shared__ __align__(16) unsigned char Vl[2 * 17408];
    const int T = threadIdx.x;
    const int lane = T & 63, wid = T >> 6;
    const int l15 = lane & 15, quad = lane >> 4;

    const int blk = blockIdx.x;      // 1024 = 16 b x 64 qtiles(64q)
    const int b = blk >> 6;
    const int q0w = (blk & 63) * 64 + wid * 16;
    const unsigned short* fb = f_ + (size_t)b * HW_N * CK_N;
    const unsigned short* gb = g_ + (size_t)b * HWP_N * CK_N;
    const unsigned short* hb = h_ + (size_t)b * CH_N * HWP_N;

    short8 ffr = ld8(fb + (size_t)(q0w + l15) * CK_N + quad * 8);

    const f32x4 zf = {0.f, 0.f, 0.f, 0.f};
    f32x4 oacc[8];   // [ct]; D row = ch(quad*4+r), col = query(l15)
    #pragma unroll
    for (int ct = 0; ct < 8; ++ct)
        oacc[ct] = f32x4{0.f, 0.f, 0.f, 0.f};
    float lsum = 0.f;

    // staging coords: ch rows sch+32i (i<4), 16B key-chunk skq (0-conflict)
    const int sch = T >> 3, skq = T & 7;
    // permuted in-tile key row for QK A-operand: l15 -> 8*(l15>>2) + (l15&3)
    const int kq = ((l15 >> 2) << 3) | (l15 & 3);

    uint4 vpre[4];
    #pragma unroll
    for (int i = 0; i < 4; ++i)
        vpre[i] = *reinterpret_cast<const uint4*>(hb + (size_t)(sch + i * 32) * HWP_N + skq * 8);
    short8 gcur[4];
    #pragma unroll
    for (int kt = 0; kt < 4; ++kt)
        gcur[kt] = ld8(gb + (size_t)(((kt >> 1) << 5) + ((kt & 1) << 2) + kq) * CK_N + quad * 8);

    for (int c = 0; c < 16; ++c) {
        unsigned char* buf = Vl + (c & 1) * 17408;
        // write chunk c's V (WAR on this buffer was cleared by iter c-1's barrier)
        #pragma unroll
        for (int i = 0; i < 4; ++i) {
            unsigned char* dst = buf + (sch + i * 32) * 136 + skq * 16;
            *reinterpret_cast<uint2*>(dst)     = uint2{vpre[i].x, vpre[i].y};
            *reinterpret_cast<uint2*>(dst + 8) = uint2{vpre[i].z, vpre[i].w};
        }
        // issue chunk c+1 global loads (land during chunk c compute)
        if (c < 15) {
            #pragma unroll
            for (int i = 0; i < 4; ++i)
                vpre[i] = *reinterpret_cast<const uint4*>(
                    hb + (size_t)(sch + i * 32) * HWP_N + (c + 1) * 64 + skq * 8);
        }
        __syncthreads();   // buf writes visible; single barrier per chunk

        // QK: sp[kt] row (quad,r) = key (kt>>1)*32 + (kt&1)*4 + 8*quad + r, col=q(l15)
        f32x4 sp[4];
        #pragma unroll
        for (int kt = 0; kt < 4; ++kt)
            sp[kt] = MFMA(gcur[kt], ffr, zf);
        if (c < 15) {
            #pragma unroll
            for (int kt = 0; kt < 4; ++kt)
                gcur[kt] = ld8(gb + (size_t)((c + 1) * 64 + ((kt >> 1) << 5) + ((kt & 1) << 2) + kq) * CK_N + quad * 8);
        }

        // exp2 fixed shift, accumulate denom, pack straight into K=32 B-frags
        unsigned pw[8];
        float lw = 0.f;
        #pragma unroll
        for (int kt = 0; kt < 4; ++kt) {
            float p0 = __builtin_amdgcn_exp2f(sp[kt][0] * 1.44269504f - 28.85390082f);
            float p1 = __builtin_amdgcn_exp2f(sp[kt][1] * 1.44269504f - 28.85390082f);
            float p2 = __builtin_amdgcn_exp2f(sp[kt][2] * 1.44269504f - 28.85390082f);
            float p3 = __builtin_amdgcn_exp2f(sp[kt][3] * 1.44269504f - 28.85390082f);
            lw += (p0 + p1) + (p2 + p3);
            pw[2 * kt]     = packrn(p0, p1);
            pw[2 * kt + 1] = packrn(p2, p3);
        }
        lsum += lw;
        // B-frag slice t: lane quad holds P[key=t*32+8*quad+j][q=l15], j=0..7
        short8 pfA = __builtin_bit_cast(short8, uint4v{pw[0], pw[1], pw[2], pw[3]});
        short8 pfB = __builtin_bit_cast(short8, uint4v{pw[4], pw[5], pw[6], pw[7]});

        // PV: A = V[ch=ct*16+l15][key=t*32+quad*8+j], two b64 reads per frag
        const int vbase = l15 * 136 + quad * 16;
        #pragma unroll
        for (int ct = 0; ct < 8; ++ct) {
            const unsigned char* p = buf + vbase + ct * 2176;
            uint2 aLo0 = *reinterpret_cast<const uint2*>(p);
            uint2 aLo1 = *reinterpret_cast<const uint2*>(p + 8);
            short8 a0 = __builtin_bit_cast(short8, uint4v{aLo0.x, aLo0.y, aLo1.x, aLo1.y});
            oacc[ct] = MFMA(a0, pfA, oacc[ct]);
            uint2 aHi0 = *reinterpret_cast<const uint2*>(p + 64);
            uint2 aHi1 = *reinterpret_cast<const uint2*>(p + 72);
            short8 a1 = __builtin_bit_cast(short8, uint4v{aHi0.x, aHi0.y, aHi1.x, aHi1.y});
            oacc[ct] = MFMA(a1, pfB, oacc[ct]);
        }
    }

    // reduce denominator across quads (lanes share query = l15), scale
    lsum += __shfl_xor(lsum, 16); lsum += __shfl_xor(lsum, 32);
    const float rl = 1.f / lsum;

    // ---- pack o (bf16, same rounding as before) into LDS [64px][264B] ----
    // Reuses Vl buffer 0 (0..16895 < 17408). No barrier needed first: after
    // chunk 15's in-loop barrier every wave only reads buffer 1 (17408..).
    unsigned char* o_lds = Vl;
    {
        const int row = wid * 16 + l15;   // block-local px
        #pragma unroll
        for (int ct = 0; ct < 8; ++ct) {
            uint2 u;
            u.x = packrn(oacc[ct][0] * rl, oacc[ct][1] * rl);
            u.y = packrn(oacc[ct][2] * rl, oacc[ct][3] * rl);
            *reinterpret_cast<uint2*>(o_lds + row * 264 + (ct * 16 + quad * 4) * 2) = u;
        }
    }
    __syncthreads();   // o_lds visible to all waves (cross-wave px reads)

    // ---- fused final conv: wave wid does oc [wid*64, wid*64+64) x 64 px ----
    const int pxb = (blk & 63) * 64;   // global px base of this block
    const int oc0 = wid * 64;
    f32x4 acc2[4][4];   // [mt][nt]; D row=px(quad*4+r), col=oc(l15)
    #pragma unroll
    for (int mt = 0; mt < 4; ++mt)
        #pragma unroll
        for (int nt = 0; nt < 4; ++nt)
            acc2[mt][nt] = f32x4{0.f, 0.f, 0.f, 0.f};

    #pragma unroll
    for (int k0 = 0; k0 < 128; k0 += 32) {
        short8 ofr[4];   // o A-frags: row px=nt*16+l15, k=k0+quad*8..+7
        #pragma unroll
        for (int nt = 0; nt < 4; ++nt) {
            const unsigned char* p = o_lds + (nt * 16 + l15) * 264 + k0 * 2 + quad * 16;
            uint2 a0 = *reinterpret_cast<const uint2*>(p);
            uint2 a1 = *reinterpret_cast<const uint2*>(p + 8);
            ofr[nt] = __builtin_bit_cast(short8, uint4v{a0.x, a0.y, a1.x, a1.y});
        }
        #pragma unroll
        for (int mt = 0; mt < 4; ++mt) {
            short8 wfr = ld8(Wv + (size_t)(oc0 + mt * 16 + l15) * CH_N + k0 + quad * 8);
            #pragma unroll
            for (int nt = 0; nt < 4; ++nt)
                acc2[mt][nt] = MFMA(ofr[nt], wfr, acc2[mt][nt]);  // A=o(px), B=Wv(oc)
        }
    }

    const float gamma = *gamma_p;
    const float* xb = x + (size_t)b * C_N * HW_N;
    float* outb = out + (size_t)b * C_N * HW_N;
    #pragma unroll
    for (int mt = 0; mt < 4; ++mt) {
        int oc = oc0 + mt * 16 + l15;
        float bvv = bv[oc];
        #pragma unroll
        for (int nt = 0; nt < 4; ++nt) {
            size_t base = (size_t)oc * HW_N + pxb + nt * 16 + quad * 4;
            float4 xv = *reinterpret_cast<const float4*>(xb + base);
            float4 ov;
            ov.x = gamma * (acc2[mt][nt][0] + bvv) + xv.x;
            ov.y = gamma * (acc2[mt][nt][1] + bvv) + xv.y;
            ov.z = gamma * (acc2[mt][nt][2] + bvv) + xv.z;
            ov.w = gamma * (acc2[mt][nt][3] + bvv) + xv.w;
            *reinterpret_cast<float4*>(outb + base) = ov;
        }
    }
}

// ---------------- launch ----------------
extern "C" void kernel_launch(void* const* d_in, const int* in_sizes, int n_in,
                              void* d_out, int out_size, void* d_ws, size_t ws_size,
                              hipStream_t stream) {
    const float* x     = (const float*)d_in[0];
    const float* wf    = (const float*)d_in[1];
    const float* bf    = (const float*)d_in[2];
    const float* wg    = (const float*)d_in[3];
    const float* bg    = (const float*)d_in[4];
    const float* wh    = (const float*)d_in[5];
    const float* bh    = (const float*)d_in[6];
    const float* wv    = (const float*)d_in[7];
    const float* bv    = (const float*)d_in[8];
    const float* gamma = (const float*)d_in[9];
    float* out = (float*)d_out;
    char* ws = (char*)d_ws;

    unsigned short* f_ = (unsigned short*)(ws);                 //  4,194,304 B
    unsigned short* g_ = (unsigned short*)(ws + 4194304);       //  1,048,576 B
    unsigned short* h_ = (unsigned short*)(ws + 5242880);       //  4,194,304 B
    unsigned short* Wc = (unsigned short*)(ws + 26214400);      //     98,304 B
    unsigned short* Wv = (unsigned short*)(ws + 26312704);      //     65,536 B

    k_prep<<<192, 256, 0, stream>>>(wf, wg, wh, wv, Wc, Wv);
    k_conv_fgh<<<1024, 256, 0, stream>>>(x, Wc, bf, bg, bh, f_, g_, h_);
    k_attn<<<1024, 256, 0, stream>>>(f_, g_, h_, Wv, bv, x, gamma, out);
}